// Round 11
// baseline (128.691 us; speedup 1.0000x reference)
//
#include <hip/hip_runtime.h>

#define DIM 4096
#define HD 128
#define NQH 32
#define NKVH 8
#define NB 8
#define MAXSEQ 4096
#define TOTALT 4096          // start_pos + 1 (start_pos fixed 4095)
#define QCOLS (NQH*HD)       // 4096
#define KVCOLS (NKVH*HD)     // 1024 floats = one full t-row (all kvh)
#define CCOLS (QCOLS + 2*KVCOLS) // 6144
#define DCH 64               // split-K d-chunk
#define KSP (DIM/DCH)        // 64
#define RT 8                 // t-rows per tile (each row = 1024 floats, all kvh)
#define NT 16                // tiles per chunk
#define CHKR (RT*NT)         // 128 rows per chunk
#define NCHK (TOTALT/CHKR)   // 32 chunks per batch -> grid 256 = 1 block/CU

typedef __attribute__((address_space(1))) const void __gvoid;
typedef __attribute__((address_space(3))) void __lvoid;
#define GLD16(g, l) __builtin_amdgcn_global_load_lds((__gvoid*)(g), (__lvoid*)(l), 16, 0, 0)
#define VMWAIT(N) asm volatile("s_waitcnt vmcnt(" #N ")" ::: "memory")
#define LGKMWAIT0 asm volatile("s_waitcnt lgkmcnt(0)" ::: "memory")
#define SCHEDBAR __builtin_amdgcn_sched_barrier(0)

// ---------------------------------------------------------------------------
// Fused GEMV partials. 128 threads, 512 cols/block (4/thread, float4 loads).
// ---------------------------------------------------------------------------
__global__ __launch_bounds__(128) void gemv4_kernel(
    const float* __restrict__ x, const float* __restrict__ wq,
    const float* __restrict__ wk, const float* __restrict__ wv,
    float* __restrict__ part, int pstride)
{
    __shared__ float xs[DCH*NB];       // [d][b]
    const int tx = threadIdx.x;
    const int d0 = blockIdx.y*DCH;
    for (int i = tx; i < DCH*NB; i += 128)          // i = b*64 + d
        xs[(i&63)*NB + (i>>6)] = x[(i>>6)*DIM + d0 + (i&63)];
    __syncthreads();

    const int colbase = blockIdx.x*512;
    const float* w; int wcols, wcol;
    if (colbase < QCOLS)               { w = wq; wcols = QCOLS;  wcol = colbase; }
    else if (colbase < QCOLS+KVCOLS)   { w = wk; wcols = KVCOLS; wcol = colbase - QCOLS; }
    else                               { w = wv; wcols = KVCOLS; wcol = colbase - QCOLS - KVCOLS; }

    const float* wp = w + (size_t)d0*wcols + wcol + tx*4;
    float4 a[NB];
    #pragma unroll
    for (int b = 0; b < NB; b++) { a[b].x=0.f; a[b].y=0.f; a[b].z=0.f; a[b].w=0.f; }

    #pragma unroll 4
    for (int dl = 0; dl < DCH; dl++) {
        float4 wv4 = *reinterpret_cast<const float4*>(wp + (size_t)dl*wcols);
        float4 x0 = *reinterpret_cast<const float4*>(&xs[dl*NB]);
        float4 x1 = *reinterpret_cast<const float4*>(&xs[dl*NB + 4]);
        a[0].x += wv4.x*x0.x; a[0].y += wv4.y*x0.x; a[0].z += wv4.z*x0.x; a[0].w += wv4.w*x0.x;
        a[1].x += wv4.x*x0.y; a[1].y += wv4.y*x0.y; a[1].z += wv4.z*x0.y; a[1].w += wv4.w*x0.y;
        a[2].x += wv4.x*x0.z; a[2].y += wv4.y*x0.z; a[2].z += wv4.z*x0.z; a[2].w += wv4.w*x0.z;
        a[3].x += wv4.x*x0.w; a[3].y += wv4.y*x0.w; a[3].z += wv4.z*x0.w; a[3].w += wv4.w*x0.w;
        a[4].x += wv4.x*x1.x; a[4].y += wv4.y*x1.x; a[4].z += wv4.z*x1.x; a[4].w += wv4.w*x1.x;
        a[5].x += wv4.x*x1.y; a[5].y += wv4.y*x1.y; a[5].z += wv4.z*x1.y; a[5].w += wv4.w*x1.y;
        a[6].x += wv4.x*x1.z; a[6].y += wv4.y*x1.z; a[6].z += wv4.z*x1.z; a[6].w += wv4.w*x1.z;
        a[7].x += wv4.x*x1.w; a[7].y += wv4.y*x1.w; a[7].z += wv4.z*x1.w; a[7].w += wv4.w*x1.w;
    }
    const int ocol = colbase + tx*4;
    #pragma unroll
    for (int b = 0; b < NB; b++)
        *reinterpret_cast<float4*>(&part[((size_t)(blockIdx.y*NB + b))*pstride + ocol]) = a[b];
}

// ---------------------------------------------------------------------------
// Reduce QKV split-K partials (float2) + RoPE on q,k.
// ---------------------------------------------------------------------------
__global__ __launch_bounds__(256) void qkv_reduce_rope(
    const float* __restrict__ part, const float* __restrict__ fc,
    const float* __restrict__ fs, float* __restrict__ q,
    float* __restrict__ knew, float* __restrict__ vnew)
{
    const int p = blockIdx.x*256 + threadIdx.x;   // 0 .. NB*CCOLS/2-1
    const int b = p / (CCOLS/2);
    const int c0 = (p % (CCOLS/2))*2;
    float s0 = 0.f, s1 = 0.f;
    const float* pb = part + (size_t)b*CCOLS + c0;
    #pragma unroll 8
    for (int ky = 0; ky < KSP; ky++) {
        float2 v = *reinterpret_cast<const float2*>(pb + (size_t)ky*NB*CCOLS);
        s0 += v.x; s1 += v.y;
    }
    float r0 = s0, r1 = s1;
    if (c0 < QCOLS + KVCOLS) {           // q or k: rope
        int i = (c0 & (HD-1)) >> 1;
        float c = fc[i], s = fs[i];
        r0 = s0*c - s1*s;
        r1 = s0*s + s1*c;
    }
    if (c0 < QCOLS) {
        *reinterpret_cast<float2*>(&q[b*QCOLS + c0]) = make_float2(r0, r1);
    } else if (c0 < QCOLS + KVCOLS) {
        *reinterpret_cast<float2*>(&knew[b*KVCOLS + (c0 - QCOLS)]) = make_float2(r0, r1);
    } else {
        *reinterpret_cast<float2*>(&vnew[b*KVCOLS + (c0 - QCOLS - KVCOLS)]) = make_float2(r0, r1);
    }
}

// ---------------------------------------------------------------------------
// Full-row flash-decode v5. Block = (chunk of 128 t-rows, b) = 256 blocks,
// 512 threads (8 waves), wave w <-> kvh w. K/V staged as FULL CONTIGUOUS
// 4KB rows (all 8 kvh at once) via global_load_lds -> pure sequential HBM
// streaming (tests the DRAM-pattern hypothesis). 8-row tiles, double-buffer
// (128 KB LDS), counted-vmcnt 3-barrier pipeline (r9), no-max softmax (r10).
// K quad-swizzled by row (pre-swizzled source, LDS-linear dest); V linear.
// Phase 1: lane=(r,seg): 4 heads x 16-float segment dot; shfl over seg.
// Phase 3: lane=d-pair; psf float4 uniform broadcast; acc per head.
// ---------------------------------------------------------------------------
__global__ __launch_bounds__(512) void attn_fullrow_kernel(
    const float* __restrict__ q, const float* __restrict__ knew,
    const float* __restrict__ vnew, const float* __restrict__ K,
    const float* __restrict__ V, float* __restrict__ pout,
    float* __restrict__ pml)
{
    __shared__ float ks[2][RT*KVCOLS];          // 2 x 32 KB, row-swizzled quads
    __shared__ float vs[2][RT*KVCOLS];          // 2 x 32 KB, linear
    __shared__ __align__(16) float psf[NKVH*RT*4]; // 1 KB [kvh][row][head]

    const int tx = threadIdx.x;
    const int chunk = blockIdx.x, b = blockIdx.y;
    const int w = tx >> 6, lane = tx & 63;      // wave = kvh
    const int r = lane >> 3, seg = lane & 7;    // row 0..7, d-segment 0..7 (16 floats)
    const size_t blkid = (size_t)b*NCHK + chunk;
    const size_t base0 = ((size_t)b*MAXSEQ + (size_t)chunk*CHKR)*KVCOLS;
    const bool lastChunk = (chunk == NCHK-1);

    // stage one 8-row tile (K swizzled-source, V linear). 8 GLD16 per wave.
    auto stage = [&](int nb, int srow, bool lastT) {
        #pragma unroll
        for (int k = 0; k < 4; k++) {
            const int Lbase = k*512 + w*64;     // wave-uniform quad slot base
            const int rr = Lbase >> 8;          // row (uniform: 64-aligned in 256)
            const int L = Lbase + lane;         // per-lane quad slot
            const int g = L & 255;              // quad within row
            const int gk = (g & ~7) | ((g & 7) ^ rr);   // pre-swizzled K source
            const float* srck = (lastT && rr == RT-1)
                ? (knew + b*KVCOLS + gk*4)
                : (K + base0 + (size_t)(srow + rr)*KVCOLS + gk*4);
            GLD16(srck, &ks[nb][(size_t)Lbase*4]);
            const float* srcv = (lastT && rr == RT-1)
                ? (vnew + b*KVCOLS + g*4)
                : (V + base0 + (size_t)(srow + rr)*KVCOLS + g*4);
            GLD16(srcv, &vs[nb][(size_t)Lbase*4]);
        }
    };

    // prologue: q segment for 4 heads -> registers (16 float4 = 16 vmcnt
    // entries, retired by the s=0 VMWAIT(8) together with tile-0's 8).
    float4 qreg[16];
    {
        #pragma unroll
        for (int hh = 0; hh < 4; hh++) {
            const float4* qg = reinterpret_cast<const float4*>(
                q + b*QCOLS + (w*4 + hh)*HD + seg*16);
            #pragma unroll
            for (int c = 0; c < 4; c++) qreg[hh*4 + c] = qg[c];
        }
    }
    stage(0, 0, false);               // tile 0 (never the last tile)

    float2 acc[4];                    // [head], lane = d-pair
    #pragma unroll
    for (int hh = 0; hh < 4; hh++) acc[hh] = make_float2(0.f, 0.f);
    float l_acc[4] = {0.f, 0.f, 0.f, 0.f};   // 8x-duplicated (seg copies); /8 at end

    for (int s = 0; s < NT; ++s) {
        const int cb = s & 1;
        if (s+1 < NT) {
            stage(cb^1, (s+1)*RT, lastChunk && (s+1 == NT-1));
            VMWAIT(8);                // tile-s (and q at s=0) landed; s+1 in flight
        } else {
            VMWAIT(0);
        }
        __builtin_amdgcn_s_barrier(); // BAR_A
        SCHEDBAR;

        // phase 1: scores for heads w*4+0..3, row r, segment seg (16 floats)
        float s4[4] = {0.f, 0.f, 0.f, 0.f};
        {
            const float* kc = ks[cb];
            #pragma unroll
            for (int c = 0; c < 4; c++) {
                int g  = w*32 + seg*4 + c;               // global quad in row
                int gs = (g & ~7) | ((g & 7) ^ r);       // swizzled LDS quad
                float4 kv = *reinterpret_cast<const float4*>(&kc[(r*256 + gs)*4]);
                #pragma unroll
                for (int hh = 0; hh < 4; hh++) {
                    float4 qv = qreg[hh*4 + c];
                    s4[hh] += kv.x*qv.x + kv.y*qv.y + kv.z*qv.z + kv.w*qv.w;
                }
            }
        }
        // reduce across the 8 segments (masks 1,2,4 stay within the 8-lane group)
        #pragma unroll
        for (int m = 1; m <= 4; m <<= 1) {
            #pragma unroll
            for (int hh = 0; hh < 4; hh++) s4[hh] += __shfl_xor(s4[hh], m, 64);
        }
        float p0 = __expf(s4[0]*0.08838834764831845f);
        float p1 = __expf(s4[1]*0.08838834764831845f);
        float p2 = __expf(s4[2]*0.08838834764831845f);
        float p3 = __expf(s4[3]*0.08838834764831845f);
        l_acc[0] += p0; l_acc[1] += p1; l_acc[2] += p2; l_acc[3] += p3;
        if (seg == 0)
            *reinterpret_cast<float4*>(&psf[(w*RT + r)*4]) = make_float4(p0, p1, p2, p3);
        LGKMWAIT0; SCHEDBAR;
        __builtin_amdgcn_s_barrier(); // BAR_B: psf ready
        SCHEDBAR;

        // phase 3: PV. lane = d-pair of the wave's 128-d slice; 8 rows
        {
            const float* vc = vs[cb];
            #pragma unroll
            for (int t = 0; t < RT; t++) {
                float4 pg = *reinterpret_cast<const float4*>(&psf[(w*RT + t)*4]);
                float2 vv = *reinterpret_cast<const float2*>(
                    &vc[t*KVCOLS + w*HD + lane*2]);
                acc[0].x += pg.x*vv.x; acc[0].y += pg.x*vv.y;
                acc[1].x += pg.y*vv.x; acc[1].y += pg.y*vv.y;
                acc[2].x += pg.z*vv.x; acc[2].y += pg.z*vv.y;
                acc[3].x += pg.w*vv.x; acc[3].y += pg.w*vv.y;
            }
        }
        LGKMWAIT0; SCHEDBAR;
        __builtin_amdgcn_s_barrier(); // BAR_C: buffers free for re-stage
        SCHEDBAR;
    }

    // epilogue: wave w writes heads w*4+0..3 directly (no cross-wave combine)
    #pragma unroll
    for (int hh = 0; hh < 4; hh++)
        *reinterpret_cast<float2*>(
            pout + blkid*4096 + (w*4 + hh)*HD + lane*2) = acc[hh];
    // l: every lane holds its row-partial copy (8 seg duplicates) -> full
    // butterfly sums 8 x (sum over rows); divide by 8.
    #pragma unroll
    for (int m = 1; m <= 32; m <<= 1) {
        #pragma unroll
        for (int hh = 0; hh < 4; hh++) l_acc[hh] += __shfl_xor(l_acc[hh], m, 64);
    }
    if (lane == 0) {
        #pragma unroll
        for (int hh = 0; hh < 4; hh++)
            pml[blkid*NQH + w*4 + hh] = l_acc[hh]*0.125f;
    }
}

// ---------------------------------------------------------------------------
// Combine across NCHK chunks (no-max softmax: plain sums).
// ---------------------------------------------------------------------------
__global__ __launch_bounds__(128) void attn_combine_kernel(
    const float* __restrict__ pout, const float* __restrict__ pml,
    float* __restrict__ attn_out)
{
    const int d = threadIdx.x;
    const int qh = blockIdx.x;
    const int b = blockIdx.y;
    float L = 0.f, acc = 0.f;
    #pragma unroll 8
    for (int i = 0; i < NCHK; i++) {
        const size_t blkid = (size_t)b*NCHK + i;
        L   += pml[blkid*NQH + qh];
        acc += pout[blkid*4096 + qh*HD + d];
    }
    attn_out[b*QCOLS + qh*HD + d] = acc / L;
}

// ---------------------------------------------------------------------------
// Final split-K reduce for wo (float2), f32 output.
// ---------------------------------------------------------------------------
__global__ __launch_bounds__(256) void wo_reduce_kernel(
    const float* __restrict__ part, float* __restrict__ out)
{
    const int g = blockIdx.x*256 + threadIdx.x;   // float2 index, 0..16383
    float sx = 0.f, sy = 0.f;
    #pragma unroll 8
    for (int ky = 0; ky < KSP; ky++) {
        float2 v = *reinterpret_cast<const float2*>(part + (size_t)ky*NB*QCOLS + g*2);
        sx += v.x; sy += v.y;
    }
    *reinterpret_cast<float2*>(out + g*2) = make_float2(sx, sy);
}

extern "C" void kernel_launch(void* const* d_in, const int* in_sizes, int n_in,
                              void* d_out, int out_size, void* d_ws, size_t ws_size,
                              hipStream_t stream)
{
    const float* x  = (const float*)d_in[0];
    // d_in[1] = start_pos (int scalar) = 4095, fixed by the problem.
    const float* fc = (const float*)d_in[2];
    const float* fs = (const float*)d_in[3];
    const float* wq = (const float*)d_in[4];
    const float* wk = (const float*)d_in[5];
    const float* wv = (const float*)d_in[6];
    const float* wo = (const float*)d_in[7];
    const float* K  = (const float*)d_in[8];
    const float* V  = (const float*)d_in[9];

    float* ws     = (float*)d_ws;
    float* q      = ws;                     // 32768
    float* knew   = ws + 32768;             // 8192
    float* vnew   = ws + 40960;             // 8192
    float* attn_o = ws + 49152;             // 32768
    float* qkvp   = ws + 81920;             // 64*8*6144 = 3,145,728
    float* pout   = ws + 3227648;           // 256*4096  = 1,048,576
    float* pml    = ws + 4276224;           // 256*32    = 8,192
    float* wop    = ws + 81920;             // aliases qkvp (time-disjoint)

    // 1. fused QKV projection partials (768 blocks = 3/CU even)
    gemv4_kernel<<<dim3(CCOLS/512, KSP), dim3(128), 0, stream>>>(x, wq, wk, wv, qkvp, CCOLS);
    // 2. reduce + RoPE
    qkv_reduce_rope<<<dim3(NB*CCOLS/2/256), dim3(256), 0, stream>>>(qkvp, fc, fs, q, knew, vnew);
    // 3. full-row flash-decode v5 (contiguous streaming; 256 blocks = 1/CU)
    attn_fullrow_kernel<<<dim3(NCHK, NB), dim3(512), 0, stream>>>(q, knew, vnew, K, V, pout, pml);
    // 4. combine (plain sums, 32 chunks)
    attn_combine_kernel<<<dim3(NQH, NB), dim3(128), 0, stream>>>(pout, pml, attn_o);
    // 5. output projection partials (512 blocks = 2/CU even)
    gemv4_kernel<<<dim3(QCOLS/512, KSP), dim3(128), 0, stream>>>(attn_o, wo, wo, wo, wop, QCOLS);
    // 6. final reduce, f32 out
    wo_reduce_kernel<<<dim3(NB*QCOLS/2/256), dim3(256), 0, stream>>>(wop, (float*)d_out);
}